// Round 9
// baseline (101.571 us; speedup 1.0000x reference)
//
#include <hip/hip_runtime.h>
#include <hip/hip_fp16.h>

namespace {

constexpr int NN   = 256;             // FFT length along each axis
constexpr int BMN  = 256 * 256 * 256; // elements per component
constexpr int LPAD = 272;             // padded float stride per line slice

typedef float f4 __attribute__((ext_vector_type(4)));

struct cpx { float re, im; };

__device__ __forceinline__ cpx cadd(cpx a, cpx b){ return cpx{a.re + b.re, a.im + b.im}; }
__device__ __forceinline__ cpx csub(cpx a, cpx b){ return cpx{a.re - b.re, a.im - b.im}; }
__device__ __forceinline__ cpx cmul(cpx a, cpx b){ return cpx{a.re*b.re - a.im*b.im, a.re*b.im + a.im*b.re}; }
__device__ __forceinline__ cpx cmuli(cpx a){ return cpx{-a.im, a.re}; }  // multiply by +i (inverse)

// radix-4 inverse butterfly: y[k] = sum_n x[n] * e^{+2pi i nk/4}
__device__ __forceinline__ void r4(cpx a, cpx b, cpx c, cpx d,
                                   cpx& y0, cpx& y1, cpx& y2, cpx& y3) {
  cpx apc = cadd(a, c), amc = csub(a, c);
  cpx bpd = cadd(b, d), bmd = csub(b, d);
  cpx ib  = cmuli(bmd);
  y0 = cadd(apc, bpd);
  y1 = cadd(amc, ib);
  y2 = csub(apc, bpd);
  y3 = csub(amc, ib);
}

// 16-point inverse DFT (unnormalized), natural order in/out, in registers.
__device__ __forceinline__ void ifft16(cpx x[16]) {
  constexpr float WC[10] = { 1.f,  0.9238795325112867f,  0.7071067811865476f,  0.3826834323650898f, 0.f,
                            -0.3826834323650898f, -0.7071067811865476f, -0.9238795325112867f, -1.f,
                            -0.9238795325112867f };
  constexpr float WS[10] = { 0.f,  0.3826834323650898f,  0.7071067811865476f,  0.9238795325112867f, 1.f,
                             0.9238795325112867f,  0.7071067811865476f,  0.3826834323650898f,  0.f,
                            -0.3826834323650898f };
  cpx B[4][4];
#pragma unroll
  for (int n1 = 0; n1 < 4; ++n1)
    r4(x[n1], x[n1 + 4], x[n1 + 8], x[n1 + 12],
       B[n1][0], B[n1][1], B[n1][2], B[n1][3]);
#pragma unroll
  for (int n1 = 1; n1 < 4; ++n1)
#pragma unroll
    for (int k2 = 1; k2 < 4; ++k2)
      B[n1][k2] = cmul(B[n1][k2], cpx{WC[n1 * k2], WS[n1 * k2]});
#pragma unroll
  for (int k2 = 0; k2 < 4; ++k2)
    r4(B[0][k2], B[1][k2], B[2][k2], B[3][k2],
       x[k2], x[k2 + 4], x[k2 + 8], x[k2 + 12]);
}

// multiply a[k1] by W256^{t*k1} = e^{+2pi i t k1/256}
__device__ __forceinline__ void twiddle256(cpx a[16], int t) {
  const float base = 0.024543692606170259f * (float)t;  // 2*pi/256 * t
#pragma unroll
  for (int k1 = 1; k1 < 16; ++k1) {
    float s, c;
    __sincosf(base * (float)k1, &s, &c);
    a[k1] = cmul(a[k1], cpx{c, s});
  }
}

// ------- K1: pure stream fp32 -> fp16(x1/256) into ws. Fill-shaped:
// grid-stride, no LDS, no barriers, no transcendental — isolates the HBM
// stream from all FFT compute (diagnostic for the rows ~2.6 TB/s anomaly).
__global__ __launch_bounds__(256)
void k_convert(const float* __restrict__ xr, const float* __restrict__ xi,
               __half* __restrict__ wr, __half* __restrict__ wi) {
  constexpr float s1 = 1.0f / 256.0f;
  const int n4  = BMN / 4;
  const int nth = gridDim.x * blockDim.x;
  const f4* xr4 = reinterpret_cast<const f4*>(xr);
  const f4* xi4 = reinterpret_cast<const f4*>(xi);
  uint2* wr2 = reinterpret_cast<uint2*>(wr);
  uint2* wi2 = reinterpret_cast<uint2*>(wi);
  for (int g = blockIdx.x * blockDim.x + threadIdx.x; g < n4; g += nth) {
    const f4 vr = xr4[g];
    const f4 vi = xi4[g];
    union { __half2 h[2]; uint2 u; } hr, hi;
    hr.h[0] = __floats2half2_rn(vr.x * s1, vr.y * s1);
    hr.h[1] = __floats2half2_rn(vr.z * s1, vr.w * s1);
    hi.h[0] = __floats2half2_rn(vi.x * s1, vi.y * s1);
    hi.h[1] = __floats2half2_rn(vi.z * s1, vi.w * s1);
    wr2[g] = hr.u;
    wi2[g] = hi.u;
  }
}

// ------- K2: row IFFT on fp16 ws, IN-PLACE, L3-resident. 16 lines/block.
// Same phase structure as the old rows kernel, but no HBM stream: reads
// 512B/wave-instr fp16, all shifts folded, writes fp16 (scale 1/256).
__global__ __launch_bounds__(256)
void k_fft_rows(__half* __restrict__ wr, __half* __restrict__ wi) {
  __shared__ float Lr[16 * LPAD];
  __shared__ float Li[16 * LPAD];
  const int tid = threadIdx.x;
  const int t   = tid & 15;
  const int ll  = tid >> 4;

  const size_t blk = (size_t)blockIdx.x * (16 * NN);
  uint2* pr = reinterpret_cast<uint2*>(wr + blk);
  uint2* pi = reinterpret_cast<uint2*>(wi + blk);

  // cooperative load fp16 -> fp32 LDS (wave covers one full line per q)
#pragma unroll
  for (int q = 0; q < 4; ++q) {
    const int fi   = (q << 8) + tid;    // uint2 index (4 halfs each)
    const int p    = fi << 2;           // half index within tile
    const int line = p >> 8;
    const int idx  = p & 255;
    union { uint2 u; __half2 h[2]; } ur, ui;
    ur.u = pr[fi];
    ui.u = pi[fi];
    const float2 r0 = __half22float2(ur.h[0]);
    const float2 r1 = __half22float2(ur.h[1]);
    const float2 i0 = __half22float2(ui.h[0]);
    const float2 i1 = __half22float2(ui.h[1]);
    *reinterpret_cast<f4*>(&Lr[line * LPAD + idx]) = (f4){r0.x, r0.y, r1.x, r1.y};
    *reinterpret_cast<f4*>(&Li[line * LPAD + idx]) = (f4){i0.x, i0.y, i1.x, i1.y};
  }
  __syncthreads();

  // comb read (ifftshift folded): a[j] = x[(j*16+t)^128] of line ll
  cpx a[16];
  {
    const float* lr = Lr + ll * LPAD;
    const float* li = Li + ll * LPAD;
#pragma unroll
    for (int j = 0; j < 16; ++j) {
      const int idx = (((j << 4) | t) ^ 128);
      a[j] = cpx{ lr[idx], li[idx] };
    }
  }
  ifft16(a);            // a[k1] = A_t[k1]
  twiddle256(a, t);     // * W256^{t*k1}
  __syncthreads();

  // 16x16 transpose (single pass, both components)
  {
    float* lr = Lr + ll * LPAD;
    float* li = Li + ll * LPAD;
#pragma unroll
    for (int k1 = 0; k1 < 16; ++k1) { lr[k1 * 17 + t] = a[k1].re; li[k1 * 17 + t] = a[k1].im; }
    __syncthreads();
#pragma unroll
    for (int n2 = 0; n2 < 16; ++n2) { a[n2].re = lr[t * 17 + n2]; a[n2].im = li[t * 17 + n2]; }
  }
  ifft16(a);            // a[k2] = X[16*k2 + t]
  __syncthreads();

  // stage result in natural line layout (fftshift folded)
  {
    float* lr = Lr + ll * LPAD;
    float* li = Li + ll * LPAD;
#pragma unroll
    for (int k = 0; k < 16; ++k) {
      const int idx = (((k << 4) | t) ^ 128);
      lr[idx] = a[k].re;
      li[idx] = a[k].im;
    }
  }
  __syncthreads();

  // pack back to fp16 in-place (second half of the 1/65536 norm)
  constexpr float s2 = 1.0f / 256.0f;
#pragma unroll
  for (int q = 0; q < 4; ++q) {
    const int fi   = (q << 8) + tid;
    const int p    = fi << 2;
    const int line = p >> 8;
    const int idx  = p & 255;
    const f4 vr = *reinterpret_cast<const f4*>(&Lr[line * LPAD + idx]);
    const f4 vi = *reinterpret_cast<const f4*>(&Li[line * LPAD + idx]);
    union { __half2 h[2]; uint2 u; } hr, hi;
    hr.h[0] = __floats2half2_rn(vr.x * s2, vr.y * s2);
    hr.h[1] = __floats2half2_rn(vr.z * s2, vr.w * s2);
    hi.h[0] = __floats2half2_rn(vi.x * s2, vi.y * s2);
    hi.h[1] = __floats2half2_rn(vi.z * s2, vi.w * s2);
    pr[fi] = hr.u;
    pi[fi] = hi.u;
  }
}

// ------- K3: column IFFT (axis -2). fp16 ws -> fp32 out (already normalized).
// 512 threads: c = tid&31 (column, lane-fastest), t = tid>>5. 32-col tiles.
// Reads hit L3 (ws resident); final stores NONTEMPORAL (dead after check).
__global__ __launch_bounds__(512)
void k_ifft_cols(const __half* __restrict__ wr, const __half* __restrict__ wi,
                 float* __restrict__ yr, float* __restrict__ yi) {
  __shared__ float lbuf[32 * 273];
  const int tid = threadIdx.x;
  const int c   = tid & 31;
  const int t   = tid >> 5;
  const int b   = blockIdx.x >> 3;
  const int c0  = (blockIdx.x & 7) << 5;
  const int base = b * 65536 + c0 + c;

  cpx a[16];
#pragma unroll
  for (int j = 0; j < 16; ++j) {
    const int m = (((j << 4) | t) ^ 128);     // ifftshift on load
    a[j] = cpx{ __half2float(wr[base + m * NN]), __half2float(wi[base + m * NN]) };
  }
  ifft16(a);
  twiddle256(a, t);

  // two-pass 16x16 transpose through single buffer (re then im)
  {
    float* L = lbuf + c * 273;
#pragma unroll
    for (int k1 = 0; k1 < 16; ++k1) L[k1 * 17 + t] = a[k1].re;
    __syncthreads();
    float br[16];
#pragma unroll
    for (int n2 = 0; n2 < 16; ++n2) br[n2] = L[t * 17 + n2];
    __syncthreads();
#pragma unroll
    for (int k1 = 0; k1 < 16; ++k1) L[k1 * 17 + t] = a[k1].im;
    __syncthreads();
#pragma unroll
    for (int n2 = 0; n2 < 16; ++n2) { a[n2].im = L[t * 17 + n2]; a[n2].re = br[n2]; }
  }

  ifft16(a);
#pragma unroll
  for (int k = 0; k < 16; ++k) {
    const int m = (((k << 4) | t) ^ 128);     // fftshift on store
    __builtin_nontemporal_store(a[k].re, &yr[base + m * NN]);
    __builtin_nontemporal_store(a[k].im, &yi[base + m * NN]);
  }
}

} // namespace

extern "C" void kernel_launch(void* const* d_in, const int* in_sizes, int n_in,
                              void* d_out, int out_size, void* d_ws, size_t ws_size,
                              hipStream_t stream) {
  const float* xr = (const float*)d_in[0];
  const float* xi = (const float*)d_in[1];
  float* yr = (float*)d_out;        // real part of output
  float* yi = yr + BMN;             // imag part of output
  __half* wr = (__half*)d_ws;       // fp16 intermediate (67 MB, fits ws)
  __half* wi = wr + BMN;

  k_convert <<<2048, 256, 0, stream>>>(xr, xi, wr, wi);   // pure HBM stream
  k_fft_rows<<<4096, 256, 0, stream>>>(wr, wi);           // L3-resident, in-place
  k_ifft_cols<<<2048, 512, 0, stream>>>(wr, wi, yr, yi);  // L3 read, NT store
}

// Round 10
// 81.702 us; speedup vs baseline: 1.2432x; 1.2432x over previous
//
#include <hip/hip_runtime.h>
#include <hip/hip_fp16.h>

namespace {

constexpr int NN   = 256;             // FFT length along each axis
constexpr int BMN  = 256 * 256 * 256; // elements per component
constexpr int LPAD = 272;             // padded float stride per line slice (>=271 for 17-stride transpose)

typedef float f4 __attribute__((ext_vector_type(4)));

struct cpx { float re, im; };

__device__ __forceinline__ cpx cadd(cpx a, cpx b){ return cpx{a.re + b.re, a.im + b.im}; }
__device__ __forceinline__ cpx csub(cpx a, cpx b){ return cpx{a.re - b.re, a.im - b.im}; }
__device__ __forceinline__ cpx cmul(cpx a, cpx b){ return cpx{a.re*b.re - a.im*b.im, a.re*b.im + a.im*b.re}; }
__device__ __forceinline__ cpx cmuli(cpx a){ return cpx{-a.im, a.re}; }  // multiply by +i (inverse)

// radix-4 inverse butterfly: y[k] = sum_n x[n] * e^{+2pi i nk/4}
__device__ __forceinline__ void r4(cpx a, cpx b, cpx c, cpx d,
                                   cpx& y0, cpx& y1, cpx& y2, cpx& y3) {
  cpx apc = cadd(a, c), amc = csub(a, c);
  cpx bpd = cadd(b, d), bmd = csub(b, d);
  cpx ib  = cmuli(bmd);
  y0 = cadd(apc, bpd);
  y1 = cadd(amc, ib);
  y2 = csub(apc, bpd);
  y3 = csub(amc, ib);
}

// 16-point inverse DFT (unnormalized), natural order in/out, in registers.
__device__ __forceinline__ void ifft16(cpx x[16]) {
  constexpr float WC[10] = { 1.f,  0.9238795325112867f,  0.7071067811865476f,  0.3826834323650898f, 0.f,
                            -0.3826834323650898f, -0.7071067811865476f, -0.9238795325112867f, -1.f,
                            -0.9238795325112867f };
  constexpr float WS[10] = { 0.f,  0.3826834323650898f,  0.7071067811865476f,  0.9238795325112867f, 1.f,
                             0.9238795325112867f,  0.7071067811865476f,  0.3826834323650898f,  0.f,
                            -0.3826834323650898f };
  cpx B[4][4];
#pragma unroll
  for (int n1 = 0; n1 < 4; ++n1)
    r4(x[n1], x[n1 + 4], x[n1 + 8], x[n1 + 12],
       B[n1][0], B[n1][1], B[n1][2], B[n1][3]);
#pragma unroll
  for (int n1 = 1; n1 < 4; ++n1)
#pragma unroll
    for (int k2 = 1; k2 < 4; ++k2)
      B[n1][k2] = cmul(B[n1][k2], cpx{WC[n1 * k2], WS[n1 * k2]});
#pragma unroll
  for (int k2 = 0; k2 < 4; ++k2)
    r4(B[0][k2], B[1][k2], B[2][k2], B[3][k2],
       x[k2], x[k2 + 4], x[k2 + 8], x[k2 + 12]);
}

// multiply a[k1] by W256^{t*k1} = e^{+2pi i t k1/256}
__device__ __forceinline__ void twiddle256(cpx a[16], int t) {
  const float base = 0.024543692606170259f * (float)t;  // 2*pi/256 * t
#pragma unroll
  for (int k1 = 1; k1 < 16; ++k1) {
    float s, c;
    __sincosf(base * (float)k1, &s, &c);
    a[k1] = cmul(a[k1], cpx{c, s});
  }
}

// ------- FUSED per-image 2D IFFT: one block = one image (256x256).
// Phase A: 4 chunks of 64 lines -> row IFFT -> fp16 ws slice (stays in L2:
//   written and read by the SAME block, ~256KB/image). Phase B: 4 tiles of
//   64 columns -> col IFFT -> fp32 nontemporal output stores.
// ws never competes for L3; input gets L3 to itself; out bypasses (nt).
__global__ __launch_bounds__(1024)
void k_ifft2d(const float* __restrict__ xr, const float* __restrict__ xi,
              __half* __restrict__ wr, __half* __restrict__ wi,
              float* __restrict__ yr, float* __restrict__ yi) {
  __shared__ float SM[2 * 64 * LPAD];   // 139264 B = 136 KiB (<160 KiB/CU)
  float* Lr = SM;
  float* Li = SM + 64 * LPAD;

  const int tid  = threadIdx.x;
  const size_t ibase = (size_t)blockIdx.x * (NN * NN);

  // ================= Phase A: row IFFTs, 64 lines per chunk =================
  {
    const int t  = tid & 15;   // n2 index within line
    const int ll = tid >> 4;   // line within chunk (0..63)
    for (int it = 0; it < 4; ++it) {
      const size_t off = ibase + (size_t)it * (64 * NN);
      const f4* sr4 = reinterpret_cast<const f4*>(xr + off);
      const f4* si4 = reinterpret_cast<const f4*>(xi + off);
      // cooperative load: 64 lines, wave = 1KB contiguous, one line per wave-q
#pragma unroll
      for (int q = 0; q < 4; ++q) {
        const int fi   = (q << 10) + tid;   // f4 index in [0,4096)
        const int line = fi >> 6;
        const int slot = fi & 63;
        *reinterpret_cast<f4*>(&Lr[line * LPAD + slot * 4]) = sr4[fi];
        *reinterpret_cast<f4*>(&Li[line * LPAD + slot * 4]) = si4[fi];
      }
      __syncthreads();

      // comb read (ifftshift folded)
      cpx a[16];
      {
        const float* lr = Lr + ll * LPAD;
        const float* li = Li + ll * LPAD;
#pragma unroll
        for (int j = 0; j < 16; ++j) {
          const int idx = (((j << 4) | t) ^ 128);
          a[j] = cpx{ lr[idx], li[idx] };
        }
      }
      ifft16(a);
      twiddle256(a, t);
      __syncthreads();

      // 16x16 transpose within own line slice
      {
        float* lr = Lr + ll * LPAD;
        float* li = Li + ll * LPAD;
#pragma unroll
        for (int k1 = 0; k1 < 16; ++k1) { lr[k1 * 17 + t] = a[k1].re; li[k1 * 17 + t] = a[k1].im; }
        __syncthreads();
#pragma unroll
        for (int n2 = 0; n2 < 16; ++n2) { a[n2].re = lr[t * 17 + n2]; a[n2].im = li[t * 17 + n2]; }
      }
      ifft16(a);
      __syncthreads();

      // stage result in natural line layout (fftshift folded)
      {
        float* lr = Lr + ll * LPAD;
        float* li = Li + ll * LPAD;
#pragma unroll
        for (int k = 0; k < 16; ++k) {
          const int idx = (((k << 4) | t) ^ 128);
          lr[idx] = a[k].re;
          li[idx] = a[k].im;
        }
      }
      __syncthreads();

      // pack to fp16 ws slice (scale = first half of 1/65536); L2-local reuse
      constexpr float s1 = 1.0f / 256.0f;
      uint2* dr = reinterpret_cast<uint2*>(wr + off);
      uint2* di = reinterpret_cast<uint2*>(wi + off);
#pragma unroll
      for (int q = 0; q < 4; ++q) {
        const int fi   = (q << 10) + tid;   // uint2 index (4 halfs)
        const int p    = fi << 2;
        const int line = p >> 8;
        const int idx  = p & 255;
        const f4 vr = *reinterpret_cast<const f4*>(&Lr[line * LPAD + idx]);
        const f4 vi = *reinterpret_cast<const f4*>(&Li[line * LPAD + idx]);
        union { __half2 h[2]; uint2 u; } hr, hi;
        hr.h[0] = __floats2half2_rn(vr.x * s1, vr.y * s1);
        hr.h[1] = __floats2half2_rn(vr.z * s1, vr.w * s1);
        hi.h[0] = __floats2half2_rn(vi.x * s1, vi.y * s1);
        hi.h[1] = __floats2half2_rn(vi.z * s1, vi.w * s1);
        dr[fi] = hr.u;
        di[fi] = hi.u;
      }
      __syncthreads();   // LDS reads done before next chunk's staging
    }
  }
  // ws writes are visible to this block after the barrier (vmcnt drained).

  // ================= Phase B: column IFFTs, 64 columns per tile =================
  {
    const int c  = tid & 63;   // column within tile
    const int tg = tid >> 6;   // position group (0..15)
    float* TR = SM;            // reuse: 64*273 floats = 69.9 KB
    for (int ct = 0; ct < 4; ++ct) {
      __syncthreads();         // TR reuse across tiles / after phase A
      const size_t base = ibase + (ct << 6) + c;

      cpx a[16];
#pragma unroll
      for (int j = 0; j < 16; ++j) {
        const int m = (((j << 4) | tg) ^ 128);   // ifftshift on load
        a[j] = cpx{ __half2float(wr[base + m * NN]), __half2float(wi[base + m * NN]) };
      }
      ifft16(a);
      twiddle256(a, tg);

      // two-pass 16x16 transpose through single buffer (re then im)
      {
        float* L = TR + c * 273;
#pragma unroll
        for (int k1 = 0; k1 < 16; ++k1) L[k1 * 17 + tg] = a[k1].re;
        __syncthreads();
        float br[16];
#pragma unroll
        for (int n2 = 0; n2 < 16; ++n2) br[n2] = L[tg * 17 + n2];
        __syncthreads();
#pragma unroll
        for (int k1 = 0; k1 < 16; ++k1) L[k1 * 17 + tg] = a[k1].im;
        __syncthreads();
#pragma unroll
        for (int n2 = 0; n2 < 16; ++n2) { a[n2].im = L[tg * 17 + n2]; a[n2].re = br[n2]; }
      }

      ifft16(a);
      constexpr float s2 = 1.0f / 256.0f;        // second half of the norm
#pragma unroll
      for (int k = 0; k < 16; ++k) {
        const int m = (((k << 4) | tg) ^ 128);   // fftshift on store
        __builtin_nontemporal_store(a[k].re * s2, &yr[base + m * NN]);
        __builtin_nontemporal_store(a[k].im * s2, &yi[base + m * NN]);
      }
    }
  }
}

} // namespace

extern "C" void kernel_launch(void* const* d_in, const int* in_sizes, int n_in,
                              void* d_out, int out_size, void* d_ws, size_t ws_size,
                              hipStream_t stream) {
  const float* xr = (const float*)d_in[0];
  const float* xi = (const float*)d_in[1];
  float* yr = (float*)d_out;        // real part of output
  float* yi = yr + BMN;             // imag part of output
  __half* wr = (__half*)d_ws;       // fp16 intermediate (67 MB), L2-transient
  __half* wi = wr + BMN;

  k_ifft2d<<<256, 1024, 0, stream>>>(xr, xi, wr, wi, yr, yi);  // 1 block = 1 image
}

// Round 11
// 79.489 us; speedup vs baseline: 1.2778x; 1.0278x over previous
//
#include <hip/hip_runtime.h>
#include <hip/hip_fp16.h>

namespace {

constexpr int NN   = 256;             // FFT length along each axis
constexpr int BMN  = 256 * 256 * 256; // elements per component
constexpr int LPAD = 272;             // padded float stride per line slice (16B-aligned: 68 float4)

typedef float f4 __attribute__((ext_vector_type(4)));

struct cpx { float re, im; };

__device__ __forceinline__ cpx cadd(cpx a, cpx b){ return cpx{a.re + b.re, a.im + b.im}; }
__device__ __forceinline__ cpx csub(cpx a, cpx b){ return cpx{a.re - b.re, a.im - b.im}; }
__device__ __forceinline__ cpx cmul(cpx a, cpx b){ return cpx{a.re*b.re - a.im*b.im, a.re*b.im + a.im*b.re}; }
__device__ __forceinline__ cpx cmuli(cpx a){ return cpx{-a.im, a.re}; }  // multiply by +i (inverse)

// radix-4 inverse butterfly: y[k] = sum_n x[n] * e^{+2pi i nk/4}
__device__ __forceinline__ void r4(cpx a, cpx b, cpx c, cpx d,
                                   cpx& y0, cpx& y1, cpx& y2, cpx& y3) {
  cpx apc = cadd(a, c), amc = csub(a, c);
  cpx bpd = cadd(b, d), bmd = csub(b, d);
  cpx ib  = cmuli(bmd);
  y0 = cadd(apc, bpd);
  y1 = cadd(amc, ib);
  y2 = csub(apc, bpd);
  y3 = csub(amc, ib);
}

// 16-point inverse DFT (unnormalized), natural order in/out, in registers.
__device__ __forceinline__ void ifft16(cpx x[16]) {
  constexpr float WC[10] = { 1.f,  0.9238795325112867f,  0.7071067811865476f,  0.3826834323650898f, 0.f,
                            -0.3826834323650898f, -0.7071067811865476f, -0.9238795325112867f, -1.f,
                            -0.9238795325112867f };
  constexpr float WS[10] = { 0.f,  0.3826834323650898f,  0.7071067811865476f,  0.9238795325112867f, 1.f,
                             0.9238795325112867f,  0.7071067811865476f,  0.3826834323650898f,  0.f,
                            -0.3826834323650898f };
  cpx B[4][4];
#pragma unroll
  for (int n1 = 0; n1 < 4; ++n1)
    r4(x[n1], x[n1 + 4], x[n1 + 8], x[n1 + 12],
       B[n1][0], B[n1][1], B[n1][2], B[n1][3]);
#pragma unroll
  for (int n1 = 1; n1 < 4; ++n1)
#pragma unroll
    for (int k2 = 1; k2 < 4; ++k2)
      B[n1][k2] = cmul(B[n1][k2], cpx{WC[n1 * k2], WS[n1 * k2]});
#pragma unroll
  for (int k2 = 0; k2 < 4; ++k2)
    r4(B[0][k2], B[1][k2], B[2][k2], B[3][k2],
       x[k2], x[k2 + 4], x[k2 + 8], x[k2 + 12]);
}

// multiply a[k1] by W256^{t*k1} = e^{+2pi i t k1/256}
__device__ __forceinline__ void twiddle256(cpx a[16], int t) {
  const float base = 0.024543692606170259f * (float)t;  // 2*pi/256 * t
#pragma unroll
  for (int k1 = 1; k1 < 16; ++k1) {
    float s, c;
    __sincosf(base * (float)k1, &s, &c);
    a[k1] = cmul(a[k1], cpx{c, s});
  }
}

// ------- kernel 1: row IFFT (last axis). fp32 in -> fp16 intermediate in d_ws.
// 16 lines/block, 256 threads. Coalesced float4 loads via LDS; LDS transpose;
// output staged in LDS, converted to fp16 (scale 1/256) and stored coalesced.
// Input loads CACHED (nt tried round 7: -3µs regression). ws stores CACHED:
// ws (67 MB) stays L3-resident for cols.
__global__ __launch_bounds__(256)
void k_ifft_rows(const float* __restrict__ xr, const float* __restrict__ xi,
                 __half* __restrict__ wr, __half* __restrict__ wi) {
  __shared__ float Lr[16 * LPAD];
  __shared__ float Li[16 * LPAD];
  const int tid = threadIdx.x;
  const int t   = tid & 15;
  const int ll  = tid >> 4;

  const size_t blk = (size_t)blockIdx.x * (16 * NN);
  const f4* sr4 = reinterpret_cast<const f4*>(xr + blk);
  const f4* si4 = reinterpret_cast<const f4*>(xi + blk);

  // cooperative vector load (1KB contiguous per wave instruction)
#pragma unroll
  for (int q = 0; q < 4; ++q) {
    const int fi   = (q << 8) + tid;
    const int line = fi >> 6;
    const int slot = fi & 63;
    *reinterpret_cast<f4*>(&Lr[line * LPAD + slot * 4]) = sr4[fi];
    *reinterpret_cast<f4*>(&Li[line * LPAD + slot * 4]) = si4[fi];
  }
  __syncthreads();

  // comb read (ifftshift folded): a[j] = x[(j*16+t)^128] of line ll
  cpx a[16];
  {
    const float* lr = Lr + ll * LPAD;
    const float* li = Li + ll * LPAD;
#pragma unroll
    for (int j = 0; j < 16; ++j) {
      const int idx = (((j << 4) | t) ^ 128);
      a[j] = cpx{ lr[idx], li[idx] };
    }
  }
  ifft16(a);            // a[k1] = A_t[k1]
  twiddle256(a, t);     // * W256^{t*k1}
  __syncthreads();

  // 16x16 transpose (single pass, both components)
  {
    float* lr = Lr + ll * LPAD;
    float* li = Li + ll * LPAD;
#pragma unroll
    for (int k1 = 0; k1 < 16; ++k1) { lr[k1 * 17 + t] = a[k1].re; li[k1 * 17 + t] = a[k1].im; }
    __syncthreads();
#pragma unroll
    for (int n2 = 0; n2 < 16; ++n2) { a[n2].re = lr[t * 17 + n2]; a[n2].im = li[t * 17 + n2]; }
  }
  ifft16(a);            // a[k2] = X[16*k2 + t]
  __syncthreads();

  // stage output in natural line layout (fftshift folded)
  {
    float* lr = Lr + ll * LPAD;
    float* li = Li + ll * LPAD;
#pragma unroll
    for (int k = 0; k < 16; ++k) {
      const int idx = (((k << 4) | t) ^ 128);
      lr[idx] = a[k].re;
      li[idx] = a[k].im;
    }
  }
  __syncthreads();

  // cooperative convert+store fp16 (scale = half of the 1/65536 norm)
  constexpr float s1 = 1.0f / 256.0f;
  uint2* dr = reinterpret_cast<uint2*>(wr) + (size_t)blockIdx.x * 1024;
  uint2* di = reinterpret_cast<uint2*>(wi) + (size_t)blockIdx.x * 1024;
#pragma unroll
  for (int q = 0; q < 4; ++q) {
    const int fi   = (q << 8) + tid;
    const int line = fi >> 6;
    const int slot = fi & 63;
    const f4 vr = *reinterpret_cast<const f4*>(&Lr[line * LPAD + slot * 4]);
    const f4 vi = *reinterpret_cast<const f4*>(&Li[line * LPAD + slot * 4]);
    union { __half2 h[2]; uint2 u; } pr, pi_;
    pr.h[0]  = __floats2half2_rn(vr.x * s1, vr.y * s1);
    pr.h[1]  = __floats2half2_rn(vr.z * s1, vr.w * s1);
    pi_.h[0] = __floats2half2_rn(vi.x * s1, vi.y * s1);
    pi_.h[1] = __floats2half2_rn(vi.z * s1, vi.w * s1);
    dr[fi] = pr.u;
    di[fi] = pi_.u;
  }
}

// ------- kernel 2: column IFFT (axis -2). fp16 intermediate -> fp32 out.
// 512 threads: c = tid&31 (column, lane-fastest), t = tid>>5. 32-col tiles.
// Reads hit L3 (ws resident); final stores NONTEMPORAL (dead after check).
__global__ __launch_bounds__(512)
void k_ifft_cols(const __half* __restrict__ wr, const __half* __restrict__ wi,
                 float* __restrict__ yr, float* __restrict__ yi) {
  __shared__ float lbuf[32 * 273];
  const int tid = threadIdx.x;
  const int c   = tid & 31;
  const int t   = tid >> 5;
  const int b   = blockIdx.x >> 3;
  const int c0  = (blockIdx.x & 7) << 5;
  const int base = b * 65536 + c0 + c;

  cpx a[16];
#pragma unroll
  for (int j = 0; j < 16; ++j) {
    const int m = (((j << 4) | t) ^ 128);     // ifftshift on load
    a[j] = cpx{ __half2float(wr[base + m * NN]), __half2float(wi[base + m * NN]) };
  }
  ifft16(a);
  twiddle256(a, t);

  // two-pass 16x16 transpose through single buffer (re then im)
  {
    float* L = lbuf + c * 273;
#pragma unroll
    for (int k1 = 0; k1 < 16; ++k1) L[k1 * 17 + t] = a[k1].re;
    __syncthreads();
    float br[16];
#pragma unroll
    for (int n2 = 0; n2 < 16; ++n2) br[n2] = L[t * 17 + n2];
    __syncthreads();
#pragma unroll
    for (int k1 = 0; k1 < 16; ++k1) L[k1 * 17 + t] = a[k1].im;
    __syncthreads();
#pragma unroll
    for (int n2 = 0; n2 < 16; ++n2) { a[n2].im = L[t * 17 + n2]; a[n2].re = br[n2]; }
  }

  ifft16(a);
  constexpr float sc = 1.0f / 256.0f;         // second half of the norm
#pragma unroll
  for (int k = 0; k < 16; ++k) {
    const int m = (((k << 4) | t) ^ 128);     // fftshift on store
    __builtin_nontemporal_store(a[k].re * sc, &yr[base + m * NN]);
    __builtin_nontemporal_store(a[k].im * sc, &yi[base + m * NN]);
  }
}

} // namespace

extern "C" void kernel_launch(void* const* d_in, const int* in_sizes, int n_in,
                              void* d_out, int out_size, void* d_ws, size_t ws_size,
                              hipStream_t stream) {
  const float* xr = (const float*)d_in[0];
  const float* xi = (const float*)d_in[1];
  float* yr = (float*)d_out;        // real part of output
  float* yi = yr + BMN;             // imag part of output
  __half* wr = (__half*)d_ws;       // fp16 intermediate (67 MB, fits ws)
  __half* wi = wr + BMN;

  k_ifft_rows<<<4096, 256, 0, stream>>>(xr, xi, wr, wi);       // 65536 lines / 16
  k_ifft_cols<<<2048, 512, 0, stream>>>(wr, wi, yr, yi);       // 256 images * 8 tiles
}